// Round 17
// baseline (160.807 us; speedup 1.0000x reference)
//
#include <hip/hip_runtime.h>
#include <hip/hip_bf16.h>

#define BLK 256
#define SCAT_NB 512        // blocks in the binning scatter pass
#define BIN_SHIFT 8        // 256 nodes per bin
#define STAGE_CAP 6144     // LDS-staged edges per bin (mean ~4080, 19-sigma headroom)

typedef unsigned short ushort_t;
typedef unsigned int uint_t;
typedef unsigned long long ull_t;
typedef __attribute__((ext_vector_type(8))) short bf16x8;
typedef __attribute__((ext_vector_type(4))) float f32x4;

static __device__ __forceinline__ float bf2f(ushort_t u) {
    return __uint_as_float((uint_t)u << 16);
}
static __device__ __forceinline__ ushort_t f2bf(float f) {
    __hip_bfloat16 h = __float2bfloat16(f);   // RNE
    return *reinterpret_cast<ushort_t*>(&h);
}

// ================= structure (R16) =================
// R16 counters: fused agg+gemm at VGPR=36, VALU 24%, HBM 25% -> gather is
// latency-bound, compiler didn't pipeline. R17: dual-stream gather (front/back
// halves of each edge list walked concurrently) = 16 loads in flight per lane.

// ---------------- fused prologue: bin_count + weight conv ----------------

__global__ __launch_bounds__(256) void k_pre(const int* __restrict__ eidx,
                                             int* __restrict__ bcnt,
                                             int nbins, int epb, int E,
                                             const float* __restrict__ W1, ushort_t* __restrict__ Wt1,
                                             const float* __restrict__ W2, ushort_t* __restrict__ Wt2,
                                             const float* __restrict__ W3, ushort_t* __restrict__ Wt3) {
    const int b = blockIdx.x;
    const int t = threadIdx.x;
    if (b < SCAT_NB) {
        __shared__ int h[256];
        h[t] = 0;
        __syncthreads();
        const int base = b * epb;
        const int lim  = min(base + epb, E);
        for (int e = base + t; e < lim; e += 256)
            atomicAdd(&h[eidx[E + e] >> BIN_SHIFT], 1);
        __syncthreads();
        if (t < nbins) bcnt[(size_t)t * SCAT_NB + b] = h[t];
    } else {
        int j = (b - SCAT_NB) * 256 + t;   // W[fin][fout] -> Wt[fout][fin] bf16
        if (j < 128 * 128) {
            int r = j / 128, c = j % 128;
            Wt1[(size_t)c * 128 + r] = f2bf(W1[j]);
        } else if (j < 128 * 128 + 128 * 64) {
            j -= 128 * 128;
            int r = j / 64, c = j % 64;
            Wt2[(size_t)c * 128 + r] = f2bf(W2[j]);
        } else if (j < 128 * 128 + 128 * 64 + 64 * 32) {
            j -= 128 * 128 + 128 * 64;
            int r = j / 32, c = j % 32;
            Wt3[(size_t)c * 64 + r] = f2bf(W3[j]);
        }
    }
}

// ---------------- scans for the bin-offset table ----------------

__global__ __launch_bounds__(256) void k_scan1(const int* __restrict__ cnt,
                                               int* rowptr, int* bsum, int n) {
    __shared__ int tile[256];
    const int t = threadIdx.x;
    const int i = blockIdx.x * 256 + t;
    int v = (i < n) ? cnt[i] : 0;
    tile[t] = v;
    __syncthreads();
    for (int off = 1; off < 256; off <<= 1) {
        int x = (t >= off) ? tile[t - off] : 0;
        __syncthreads();
        tile[t] += x;
        __syncthreads();
    }
    if (i < n) rowptr[i] = tile[t] - v;
    if (t == 255) bsum[blockIdx.x] = tile[255];
}

// single block, arbitrary n (serial tiles with carry), in-place exclusive
__global__ __launch_bounds__(256) void k_scan2x(int* a, int n) {
    __shared__ int tile[256];
    __shared__ int carry_s;
    const int t = threadIdx.x;
    if (t == 0) carry_s = 0;
    __syncthreads();
    for (int base = 0; base < n; base += 256) {
        int i = base + t;
        int v = (i < n) ? a[i] : 0;
        tile[t] = v;
        __syncthreads();
        for (int off = 1; off < 256; off <<= 1) {
            int x = (t >= off) ? tile[t - off] : 0;
            __syncthreads();
            tile[t] += x;
            __syncthreads();
        }
        int carry = carry_s;
        if (i < n) a[i] = carry + tile[t] - v;
        __syncthreads();
        if (t == 255) carry_s = carry + tile[255];
        __syncthreads();
    }
}

// consumers reconstruct global offsets as ebofs[idx] + bsumB[idx>>8]

// ---------------- binned edge scatter (8B packed: (s<<8)|(d&255), w) ----------------

__global__ __launch_bounds__(256) void k_bin_scatter(const int* __restrict__ eidx,
                                                     const float* __restrict__ ea,
                                                     const int* __restrict__ ebofs,
                                                     const int* __restrict__ bsumB,
                                                     uint2* __restrict__ binned,
                                                     int nbins, int epb, int E) {
    __shared__ int h[256];
    __shared__ int lofs[256];
    const int t = threadIdx.x;
    h[t] = 0;
    if (t < nbins) {
        int idx = t * SCAT_NB + blockIdx.x;
        lofs[t] = ebofs[idx] + bsumB[idx >> 8];
    }
    __syncthreads();
    const int base = blockIdx.x * epb;
    const int lim  = min(base + epb, E);
    for (int e = base + t; e < lim; e += 256) {
        int s = eidx[e];
        int d = eidx[E + e];
        float w = ea[e];
        int bin = d >> BIN_SHIFT;
        int r = atomicAdd(&h[bin], 1);      // LDS-local rank
        int pos = lofs[bin] + r;
        binned[pos] = make_uint2(((uint_t)s << 8) | (uint_t)(d & 255), __float_as_uint(w));
    }
}

// ---------------- fused per-bin hist + rowptr + dinv + CSR emit ----------------

__global__ __launch_bounds__(256) void k_bin_finish(const uint2* __restrict__ binned,
                                                    const int* __restrict__ ebofs,
                                                    const int* __restrict__ bsumB,
                                                    float* __restrict__ dinv,
                                                    int* __restrict__ rowptr,
                                                    int* __restrict__ csr_src,
                                                    float* __restrict__ csr_val,
                                                    int nbins, int N, int E) {
    __shared__ uint2 stage[STAGE_CAP];   // 48 KB
    __shared__ ull_t hs[256];
    __shared__ int   sc[256];
    __shared__ int   rp[256];
    __shared__ float dl[256];
    __shared__ int   c2[256];
    const int t = threadIdx.x;
    const int b = blockIdx.x;
    hs[t] = 0ull;
    c2[t] = 0;
    __syncthreads();
    const int i0 = b * SCAT_NB;
    const int start = ebofs[i0] + bsumB[i0 >> 8];
    int end = E;
    if (b + 1 < nbins) {
        int i1 = (b + 1) * SCAT_NB;
        end = ebofs[i1] + bsumB[i1 >> 8];
    }
    const int cnt = end - start;
    const bool fits = (cnt <= STAGE_CAP);

    if (fits) {
        for (int i = t; i < cnt; i += 256) {
            uint2 p = binned[start + i];
            stage[i] = p;
            atomicAdd(&hs[p.x & 255],
                      (1ull << 40) | (ull_t)(__uint_as_float(p.y) * 4294967296.0f));
        }
    } else {
        for (int i = start + t; i < end; i += 256) {
            uint2 p = binned[i];
            atomicAdd(&hs[p.x & 255],
                      (1ull << 40) | (ull_t)(__uint_as_float(p.y) * 4294967296.0f));
        }
    }
    __syncthreads();

    int v = (int)(hs[t] >> 40);
    sc[t] = v;
    __syncthreads();
    for (int off = 1; off < 256; off <<= 1) {
        int x = (t >= off) ? sc[t - off] : 0;
        __syncthreads();
        sc[t] += x;
        __syncthreads();
    }
    {
        ull_t s = hs[t];
        float dg = 1.0f + (float)(s & ((1ull << 40) - 1)) * (1.0f / 4294967296.0f);
        float di = rsqrtf(dg);
        dl[t] = di;
        rp[t] = start + sc[t] - v;
        const int node = (b << BIN_SHIFT) + t;
        if (node < N) {
            dinv[node]   = di;
            rowptr[node] = rp[t];
        }
        if (b == 0 && t == 0) rowptr[N] = E;
    }
    __syncthreads();

    if (fits) {
        for (int i = t; i < cnt; i += 256) {
            uint2 p = stage[i];
            int d8 = p.x & 255;
            int r = atomicAdd(&c2[d8], 1);
            int pos = rp[d8] + r;
            csr_src[pos] = (int)(p.x >> 8);
            csr_val[pos] = __uint_as_float(p.y) * dl[d8];
        }
    } else {
        for (int i = start + t; i < end; i += 256) {
            uint2 p = binned[i];
            int d8 = p.x & 255;
            int r = atomicAdd(&c2[d8], 1);
            int pos = rp[d8] + r;
            csr_src[pos] = (int)(p.x >> 8);
            csr_val[pos] = __uint_as_float(p.y) * dl[d8];
        }
    }
}

// ---------------- gather-accumulate body (dual-stream, 16 loads in flight) ----------------
// R17: walk the front and back halves of the edge list concurrently -> 2x MLP.

template <int FIN>
static __device__ __forceinline__ void agg_body(const ushort_t* __restrict__ Hf,
                                                const int* __restrict__ csr_src,
                                                const float* __restrict__ csr_val,
                                                int e0, int e1,
                                                float& a0, float& a1, float& a2, float& a3) {
    const int len  = e1 - e0;
    const int half = (len >> 4) << 3;       // per-stream span, multiple of 8
    int e = e0;                              // stream A
    int f = e0 + half;                       // stream B
    const int eAend = e0 + half;
    for (; e < eAend; e += 8, f += 8) {
        int   sA0 = csr_src[e+0], sA1 = csr_src[e+1], sA2 = csr_src[e+2], sA3 = csr_src[e+3];
        int   sA4 = csr_src[e+4], sA5 = csr_src[e+5], sA6 = csr_src[e+6], sA7 = csr_src[e+7];
        int   sB0 = csr_src[f+0], sB1 = csr_src[f+1], sB2 = csr_src[f+2], sB3 = csr_src[f+3];
        int   sB4 = csr_src[f+4], sB5 = csr_src[f+5], sB6 = csr_src[f+6], sB7 = csr_src[f+7];
        float vA0 = csr_val[e+0], vA1 = csr_val[e+1], vA2 = csr_val[e+2], vA3 = csr_val[e+3];
        float vA4 = csr_val[e+4], vA5 = csr_val[e+5], vA6 = csr_val[e+6], vA7 = csr_val[e+7];
        float vB0 = csr_val[f+0], vB1 = csr_val[f+1], vB2 = csr_val[f+2], vB3 = csr_val[f+3];
        float vB4 = csr_val[f+4], vB5 = csr_val[f+5], vB6 = csr_val[f+6], vB7 = csr_val[f+7];
        ushort4 mA0 = *(const ushort4*)(Hf + (size_t)sA0 * FIN);
        ushort4 mA1 = *(const ushort4*)(Hf + (size_t)sA1 * FIN);
        ushort4 mA2 = *(const ushort4*)(Hf + (size_t)sA2 * FIN);
        ushort4 mA3 = *(const ushort4*)(Hf + (size_t)sA3 * FIN);
        ushort4 mA4 = *(const ushort4*)(Hf + (size_t)sA4 * FIN);
        ushort4 mA5 = *(const ushort4*)(Hf + (size_t)sA5 * FIN);
        ushort4 mA6 = *(const ushort4*)(Hf + (size_t)sA6 * FIN);
        ushort4 mA7 = *(const ushort4*)(Hf + (size_t)sA7 * FIN);
        ushort4 mB0 = *(const ushort4*)(Hf + (size_t)sB0 * FIN);
        ushort4 mB1 = *(const ushort4*)(Hf + (size_t)sB1 * FIN);
        ushort4 mB2 = *(const ushort4*)(Hf + (size_t)sB2 * FIN);
        ushort4 mB3 = *(const ushort4*)(Hf + (size_t)sB3 * FIN);
        ushort4 mB4 = *(const ushort4*)(Hf + (size_t)sB4 * FIN);
        ushort4 mB5 = *(const ushort4*)(Hf + (size_t)sB5 * FIN);
        ushort4 mB6 = *(const ushort4*)(Hf + (size_t)sB6 * FIN);
        ushort4 mB7 = *(const ushort4*)(Hf + (size_t)sB7 * FIN);
        a0 += vA0 * bf2f(mA0.x); a1 += vA0 * bf2f(mA0.y); a2 += vA0 * bf2f(mA0.z); a3 += vA0 * bf2f(mA0.w);
        a0 += vA1 * bf2f(mA1.x); a1 += vA1 * bf2f(mA1.y); a2 += vA1 * bf2f(mA1.z); a3 += vA1 * bf2f(mA1.w);
        a0 += vA2 * bf2f(mA2.x); a1 += vA2 * bf2f(mA2.y); a2 += vA2 * bf2f(mA2.z); a3 += vA2 * bf2f(mA2.w);
        a0 += vA3 * bf2f(mA3.x); a1 += vA3 * bf2f(mA3.y); a2 += vA3 * bf2f(mA3.z); a3 += vA3 * bf2f(mA3.w);
        a0 += vA4 * bf2f(mA4.x); a1 += vA4 * bf2f(mA4.y); a2 += vA4 * bf2f(mA4.z); a3 += vA4 * bf2f(mA4.w);
        a0 += vA5 * bf2f(mA5.x); a1 += vA5 * bf2f(mA5.y); a2 += vA5 * bf2f(mA5.z); a3 += vA5 * bf2f(mA5.w);
        a0 += vA6 * bf2f(mA6.x); a1 += vA6 * bf2f(mA6.y); a2 += vA6 * bf2f(mA6.z); a3 += vA6 * bf2f(mA6.w);
        a0 += vA7 * bf2f(mA7.x); a1 += vA7 * bf2f(mA7.y); a2 += vA7 * bf2f(mA7.z); a3 += vA7 * bf2f(mA7.w);
        a0 += vB0 * bf2f(mB0.x); a1 += vB0 * bf2f(mB0.y); a2 += vB0 * bf2f(mB0.z); a3 += vB0 * bf2f(mB0.w);
        a0 += vB1 * bf2f(mB1.x); a1 += vB1 * bf2f(mB1.y); a2 += vB1 * bf2f(mB1.z); a3 += vB1 * bf2f(mB1.w);
        a0 += vB2 * bf2f(mB2.x); a1 += vB2 * bf2f(mB2.y); a2 += vB2 * bf2f(mB2.z); a3 += vB2 * bf2f(mB2.w);
        a0 += vB3 * bf2f(mB3.x); a1 += vB3 * bf2f(mB3.y); a2 += vB3 * bf2f(mB3.z); a3 += vB3 * bf2f(mB3.w);
        a0 += vB4 * bf2f(mB4.x); a1 += vB4 * bf2f(mB4.y); a2 += vB4 * bf2f(mB4.z); a3 += vB4 * bf2f(mB4.w);
        a0 += vB5 * bf2f(mB5.x); a1 += vB5 * bf2f(mB5.y); a2 += vB5 * bf2f(mB5.z); a3 += vB5 * bf2f(mB5.w);
        a0 += vB6 * bf2f(mB6.x); a1 += vB6 * bf2f(mB6.y); a2 += vB6 * bf2f(mB6.z); a3 += vB6 * bf2f(mB6.w);
        a0 += vB7 * bf2f(mB7.x); a1 += vB7 * bf2f(mB7.y); a2 += vB7 * bf2f(mB7.z); a3 += vB7 * bf2f(mB7.w);
    }
    // tail: [e0 + 2*half, e1)  (at most 15 edges)
    e = e0 + 2 * half;
    for (; e + 8 <= e1; e += 8) {
        int   s0 = csr_src[e+0], s1 = csr_src[e+1], s2 = csr_src[e+2], s3 = csr_src[e+3];
        int   s4 = csr_src[e+4], s5 = csr_src[e+5], s6 = csr_src[e+6], s7 = csr_src[e+7];
        float v0 = csr_val[e+0], v1 = csr_val[e+1], v2 = csr_val[e+2], v3 = csr_val[e+3];
        float v4 = csr_val[e+4], v5 = csr_val[e+5], v6 = csr_val[e+6], v7 = csr_val[e+7];
        ushort4 m0 = *(const ushort4*)(Hf + (size_t)s0 * FIN);
        ushort4 m1 = *(const ushort4*)(Hf + (size_t)s1 * FIN);
        ushort4 m2 = *(const ushort4*)(Hf + (size_t)s2 * FIN);
        ushort4 m3 = *(const ushort4*)(Hf + (size_t)s3 * FIN);
        ushort4 m4 = *(const ushort4*)(Hf + (size_t)s4 * FIN);
        ushort4 m5 = *(const ushort4*)(Hf + (size_t)s5 * FIN);
        ushort4 m6 = *(const ushort4*)(Hf + (size_t)s6 * FIN);
        ushort4 m7 = *(const ushort4*)(Hf + (size_t)s7 * FIN);
        a0 += v0 * bf2f(m0.x); a1 += v0 * bf2f(m0.y); a2 += v0 * bf2f(m0.z); a3 += v0 * bf2f(m0.w);
        a0 += v1 * bf2f(m1.x); a1 += v1 * bf2f(m1.y); a2 += v1 * bf2f(m1.z); a3 += v1 * bf2f(m1.w);
        a0 += v2 * bf2f(m2.x); a1 += v2 * bf2f(m2.y); a2 += v2 * bf2f(m2.z); a3 += v2 * bf2f(m2.w);
        a0 += v3 * bf2f(m3.x); a1 += v3 * bf2f(m3.y); a2 += v3 * bf2f(m3.z); a3 += v3 * bf2f(m3.w);
        a0 += v4 * bf2f(m4.x); a1 += v4 * bf2f(m4.y); a2 += v4 * bf2f(m4.z); a3 += v4 * bf2f(m4.w);
        a0 += v5 * bf2f(m5.x); a1 += v5 * bf2f(m5.y); a2 += v5 * bf2f(m5.z); a3 += v5 * bf2f(m5.w);
        a0 += v6 * bf2f(m6.x); a1 += v6 * bf2f(m6.y); a2 += v6 * bf2f(m6.z); a3 += v6 * bf2f(m6.w);
        a0 += v7 * bf2f(m7.x); a1 += v7 * bf2f(m7.y); a2 += v7 * bf2f(m7.z); a3 += v7 * bf2f(m7.w);
    }
    for (; e + 2 <= e1; e += 2) {
        int   s0 = csr_src[e+0], s1 = csr_src[e+1];
        float v0 = csr_val[e+0], v1 = csr_val[e+1];
        ushort4 m0 = *(const ushort4*)(Hf + (size_t)s0 * FIN);
        ushort4 m1 = *(const ushort4*)(Hf + (size_t)s1 * FIN);
        a0 += v0 * bf2f(m0.x); a1 += v0 * bf2f(m0.y); a2 += v0 * bf2f(m0.z); a3 += v0 * bf2f(m0.w);
        a0 += v1 * bf2f(m1.x); a1 += v1 * bf2f(m1.y); a2 += v1 * bf2f(m1.z); a3 += v1 * bf2f(m1.w);
    }
    if (e < e1) {
        int   s0 = csr_src[e];
        float v0 = csr_val[e];
        ushort4 m0 = *(const ushort4*)(Hf + (size_t)s0 * FIN);
        a0 += v0 * bf2f(m0.x); a1 += v0 * bf2f(m0.y); a2 += v0 * bf2f(m0.z); a3 += v0 * bf2f(m0.w);
    }
}

// ---------------- FUSED agg + gemm: G = relu(agg(H')+b); C = dinv*(G @ Wt^T) ----------------

template <int FIN, int FOUT>
__global__ __launch_bounds__(256) void k_agg_gemm(const ushort_t* __restrict__ H,
                                                  const float* __restrict__ dinv,
                                                  const int* __restrict__ rowptr,
                                                  const int* __restrict__ csr_src,
                                                  const float* __restrict__ csr_val,
                                                  const float* __restrict__ bias,
                                                  const ushort_t* __restrict__ Wt,
                                                  ushort_t* __restrict__ C, int n) {
    constexpr int PAD = 8;
    __shared__ ushort_t Gs[32][FIN + PAD];
    constexpr int LPN = FIN / 4;       // lanes per node: 32 / 16
    constexpr int NPW = 64 / LPN;      // nodes per wave: 2 / 4
    constexpr int NPB = NPW * 4;       // nodes per block pass: 8 / 16
    constexpr int NPASS = 32 / NPB;    // 4 / 2
    constexpr int NT = FOUT / 16;      // col tiles: 4 / 2
    constexpr int NK = FIN / 32;       // K steps: 4 / 2

    const int wave = threadIdx.x >> 6;
    const int lane = threadIdx.x & 63;
    const int r0 = blockIdx.x * 32;
    const int sub = lane / LPN;
    const int f4  = lane % LPN;
    const ushort_t* __restrict__ Hf = H + 4 * f4;

    // ---- phase A: aggregate 32 nodes into LDS ----
#pragma unroll
    for (int p = 0; p < NPASS; ++p) {
        const int nb = p * NPB + wave * NPW + sub;
        const int node = r0 + nb;
        float a0 = 0.f, a1 = 0.f, a2 = 0.f, a3 = 0.f;
        if (node < n) {
            const float sn = dinv[node];
            ushort4 hv = *(const ushort4*)(Hf + (size_t)node * FIN);
            a0 = sn * bf2f(hv.x); a1 = sn * bf2f(hv.y);
            a2 = sn * bf2f(hv.z); a3 = sn * bf2f(hv.w);
            agg_body<FIN>(Hf, csr_src, csr_val, rowptr[node], rowptr[node + 1], a0, a1, a2, a3);
            float4 bv = *(const float4*)(bias + 4 * f4);
            a0 = fmaxf(a0 + bv.x, 0.f); a1 = fmaxf(a1 + bv.y, 0.f);
            a2 = fmaxf(a2 + bv.z, 0.f); a3 = fmaxf(a3 + bv.w, 0.f);
        }
        *(ushort4*)(&Gs[nb][4 * f4]) = make_ushort4(f2bf(a0), f2bf(a1), f2bf(a2), f2bf(a3));
    }
    __syncthreads();

    // ---- phase B: 32-row MFMA from LDS ----
    const int l15 = lane & 15;
    const int kg  = lane >> 4;
    for (int item = wave; item < 2 * NT; item += 4) {
        const int g  = item / NT;      // row group
        const int ct = item % NT;      // col tile
        f32x4 acc = (f32x4)(0.0f);
        const ushort_t* Bp = Wt + (size_t)(ct * 16 + l15) * FIN + kg * 8;
        const int arow = g * 16 + l15;
#pragma unroll
        for (int ks = 0; ks < NK; ++ks) {
            bf16x8 a = *(const bf16x8*)(&Gs[arow][kg * 8 + ks * 32]);
            bf16x8 b = *(const bf16x8*)(Bp + ks * 32);
            acc = __builtin_amdgcn_mfma_f32_16x16x32_bf16(a, b, acc, 0, 0, 0);
        }
        const int rbase = r0 + g * 16 + kg * 4;
#pragma unroll
        for (int j = 0; j < 4; ++j) {
            int row = rbase + j;
            if (row < n)
                C[(size_t)row * FOUT + ct * 16 + l15] = f2bf(acc[j] * dinv[row]);
        }
    }
}

// ---------------- MFMA GEMM (layer 1): C = dinv * (x(f32) @ Wt^T) ----------------

template <int FIN, int FOUT>
__global__ __launch_bounds__(256) void k_gemm_f32(const float* __restrict__ A,
                                                  const ushort_t* __restrict__ Wt,
                                                  const float* __restrict__ dinv,
                                                  ushort_t* __restrict__ C, int n) {
    constexpr int NT = FOUT / 16;
    constexpr int NK = FIN / 32;
    const int wave = threadIdx.x >> 6;
    const int lane = threadIdx.x & 63;
    const int r0 = (blockIdx.x * 4 + wave) * 32;
    if (r0 >= n) return;

    const int l15 = lane & 15;
    const int kg  = lane >> 4;
    const int arow0 = min(r0 + l15, n - 1);
    const int arow1 = min(r0 + 16 + l15, n - 1);

    f32x4 acc0[NT], acc1[NT];
#pragma unroll
    for (int c = 0; c < NT; ++c) { acc0[c] = (f32x4)(0.0f); acc1[c] = (f32x4)(0.0f); }

    const ushort_t* Bp = Wt + (size_t)l15 * FIN + kg * 8;

#pragma unroll 1   // keep rolled: full unroll hoists all B loads -> spill (R1 lesson)
    for (int ks = 0; ks < NK; ++ks) {
        bf16x8 a0, a1;
        const float* p0 = A + (size_t)arow0 * FIN + kg * 8 + ks * 32;
        const float* p1 = A + (size_t)arow1 * FIN + kg * 8 + ks * 32;
        float4 u0 = *(const float4*)p0, u1 = *(const float4*)(p0 + 4);
        float4 w0 = *(const float4*)p1, w1 = *(const float4*)(p1 + 4);
        a0[0] = (short)f2bf(u0.x); a0[1] = (short)f2bf(u0.y);
        a0[2] = (short)f2bf(u0.z); a0[3] = (short)f2bf(u0.w);
        a0[4] = (short)f2bf(u1.x); a0[5] = (short)f2bf(u1.y);
        a0[6] = (short)f2bf(u1.z); a0[7] = (short)f2bf(u1.w);
        a1[0] = (short)f2bf(w0.x); a1[1] = (short)f2bf(w0.y);
        a1[2] = (short)f2bf(w0.z); a1[3] = (short)f2bf(w0.w);
        a1[4] = (short)f2bf(w1.x); a1[5] = (short)f2bf(w1.y);
        a1[6] = (short)f2bf(w1.z); a1[7] = (short)f2bf(w1.w);
#pragma unroll
        for (int c = 0; c < NT; ++c) {
            bf16x8 bfr = *(const bf16x8*)(Bp + (size_t)c * 16 * FIN + ks * 32);
            acc0[c] = __builtin_amdgcn_mfma_f32_16x16x32_bf16(a0, bfr, acc0[c], 0, 0, 0);
            acc1[c] = __builtin_amdgcn_mfma_f32_16x16x32_bf16(a1, bfr, acc1[c], 0, 0, 0);
        }
    }

#pragma unroll
    for (int g = 0; g < 2; ++g) {
        const int rbase = r0 + g * 16 + kg * 4;
#pragma unroll
        for (int j = 0; j < 4; ++j) {
            int row = rbase + j;
            if (row < n) {
                float dscale = dinv[row];
#pragma unroll
                for (int c = 0; c < NT; ++c) {
                    float val = (g == 0) ? acc0[c][j] : acc1[c][j];
                    C[(size_t)row * FOUT + c * 16 + l15] = f2bf(val * dscale);
                }
            }
        }
    }
}

// ---------------- final aggregation (layer 3, f32 out, no relu) ----------------

template <int FIN>
__global__ __launch_bounds__(256) void k_agg_final(const ushort_t* __restrict__ H,
                                                   const float* __restrict__ dinv,
                                                   const int* __restrict__ rowptr,
                                                   const int* __restrict__ csr_src,
                                                   const float* __restrict__ csr_val,
                                                   const float* __restrict__ bias,
                                                   float* __restrict__ out, int n) {
    constexpr int LPN = FIN / 4;
    constexpr int NPW = 64 / LPN;
    const int wave = threadIdx.x >> 6;
    const int lane = threadIdx.x & 63;
    const int sub  = lane / LPN;
    const int f4   = lane % LPN;
    const int node = (blockIdx.x * 4 + wave) * NPW + sub;
    if (node >= n) return;

    const ushort_t* __restrict__ Hf = H + 4 * f4;
    const float sn = dinv[node];
    ushort4 hv = *(const ushort4*)(Hf + (size_t)node * FIN);
    float a0 = sn * bf2f(hv.x);
    float a1 = sn * bf2f(hv.y);
    float a2 = sn * bf2f(hv.z);
    float a3 = sn * bf2f(hv.w);

    agg_body<FIN>(Hf, csr_src, csr_val, rowptr[node], rowptr[node + 1], a0, a1, a2, a3);

    float4 bv = *(const float4*)(bias + 4 * f4);
    a0 += bv.x; a1 += bv.y; a2 += bv.z; a3 += bv.w;
    *(float4*)(out + (size_t)node * FIN + 4 * f4) = make_float4(a0, a1, a2, a3);
}

// ---------------- launch ----------------

extern "C" void kernel_launch(void* const* d_in, const int* in_sizes, int n_in,
                              void* d_out, int out_size, void* d_ws, size_t ws_size,
                              hipStream_t stream) {
    const float* x    = (const float*)d_in[0];
    const int*   eidx = (const int*)d_in[1];
    const float* ea   = (const float*)d_in[2];
    const float* W1   = (const float*)d_in[3];
    const float* b1   = (const float*)d_in[4];
    const float* W2   = (const float*)d_in[5];
    const float* b2   = (const float*)d_in[6];
    const float* W3   = (const float*)d_in[7];
    const float* b3   = (const float*)d_in[8];

    const int N = in_sizes[0] / 128;
    const int E = in_sizes[2];

    const int nbins = (N + 255) >> BIN_SHIFT;            // 196 for N=50000 (<=256)
    const int epb   = (E + SCAT_NB - 1) / SCAT_NB;       // edges per scatter block
    const int nbc   = nbins * SCAT_NB;                   // bcnt/ebofs length
    const int gBC   = (nbc + BLK - 1) / BLK;

    char*  base = (char*)d_ws;
    size_t off  = 0;
    auto carve = [&](size_t nbytes) -> void* {
        void* p = base + off;
        off = (off + nbytes + 255) & ~(size_t)255;
        return p;
    };
    int*   bcnt      = (int*)  carve((size_t)nbc * 4);
    int*   ebofs     = (int*)  carve((size_t)nbc * 4);
    int*   bsumB     = (int*)  carve((size_t)512 * 4);
    uint2* binned    = (uint2*)carve((size_t)E * 8);
    float* dinv      = (float*)carve((size_t)N * 4);
    int*   rowptr    = (int*)  carve((size_t)(N + 1) * 4);
    int*   csr_src   = (int*)  carve((size_t)E * 4);
    float* csr_val   = (float*)carve((size_t)E * 4);
    ushort_t* bufA   = (ushort_t*)carve((size_t)N * 128 * 2);   // bf16: H'1 / H'3
    ushort_t* bufB   = (ushort_t*)carve((size_t)N * 64 * 2);    // bf16: H'2
    ushort_t* Wt1    = (ushort_t*)carve((size_t)128 * 128 * 2);
    ushort_t* Wt2    = (ushort_t*)carve((size_t)64 * 128 * 2);
    ushort_t* Wt3    = (ushort_t*)carve((size_t)32 * 64 * 2);
    (void)ws_size;

    const int wtot = 128 * 128 + 128 * 64 + 64 * 32;
    const int gPre = SCAT_NB + (wtot + 255) / 256;
    const int gR  = (N + 127) / 128;                     // gemm1 blocks (128 rows/block)
    const int gF  = (N + 31) / 32;                       // fused agg+gemm blocks (32 rows)

    // preprocessing (5 dispatches, scan-based, no global atomics)
    k_pre<<<gPre, BLK, 0, stream>>>(eidx, bcnt, nbins, epb, E, W1, Wt1, W2, Wt2, W3, Wt3);
    k_scan1<<<gBC, BLK, 0, stream>>>(bcnt, ebofs, bsumB, nbc);
    k_scan2x<<<1, BLK, 0, stream>>>(bsumB, gBC);
    k_bin_scatter<<<SCAT_NB, BLK, 0, stream>>>(eidx, ea, ebofs, bsumB, binned, nbins, epb, E);
    k_bin_finish<<<nbins, BLK, 0, stream>>>(binned, ebofs, bsumB, dinv, rowptr,
                                            csr_src, csr_val, nbins, N, E);

    // layer 1 GEMM: H'1 = dinv * (x @ W1)   (reads f32 x directly)
    k_gemm_f32<128, 128><<<gR, BLK, 0, stream>>>(x, Wt1, dinv, bufA, N);

    // fused: G2 = relu(agg(H'1)+b1); H'2 = dinv*(G2 @ W2)
    k_agg_gemm<128, 64><<<gF, BLK, 0, stream>>>(bufA, dinv, rowptr, csr_src, csr_val,
                                                b1, Wt2, bufB, N);

    // fused: G3 = relu(agg(H'2)+b2); H'3 = dinv*(G3 @ W3)
    k_agg_gemm<64, 32><<<gF, BLK, 0, stream>>>(bufB, dinv, rowptr, csr_src, csr_val,
                                               b2, Wt3, bufA, N);

    // final: out = agg(H'3) + b3   (f32, no relu)
    k_agg_final<32><<<(N + 31) / 32, BLK, 0, stream>>>(bufA, dinv, rowptr, csr_src, csr_val,
                                                       b3, (float*)d_out, N);
}

// Round 18
// 132.273 us; speedup vs baseline: 1.2157x; 1.2157x over previous
//
#include <hip/hip_runtime.h>
#include <hip/hip_bf16.h>

#define BLK 256
#define SCAT_NB 512        // blocks in the binning scatter pass
#define BIN_SHIFT 8        // 256 nodes per bin
#define STAGE_CAP 6144     // LDS-staged edges per bin (mean ~4080, 19-sigma headroom)

typedef unsigned short ushort_t;
typedef unsigned int uint_t;
typedef unsigned long long ull_t;
typedef __attribute__((ext_vector_type(8))) short bf16x8;
typedef __attribute__((ext_vector_type(8))) unsigned short ushort8_t;
typedef __attribute__((ext_vector_type(4))) float f32x4;

static __device__ __forceinline__ float bf2f(ushort_t u) {
    return __uint_as_float((uint_t)u << 16);
}
static __device__ __forceinline__ ushort_t f2bf(float f) {
    __hip_bfloat16 h = __float2bfloat16(f);   // RNE
    return *reinterpret_cast<ushort_t*>(&h);
}

// ================= structure (R17) =================
// R17 post-mortem: dual-stream gather REGRESSED (worse compiler scheduling,
// occupancy 48->30%). Reverted to single-stream; instead widened per-lane
// gathers to ushort8 (16B/lane, G13 sweet spot): half the load instructions,
// 2x bytes-in-flight, same 256B/edge coalescing.

// ---------------- fused prologue: bin_count + weight conv ----------------

__global__ __launch_bounds__(256) void k_pre(const int* __restrict__ eidx,
                                             int* __restrict__ bcnt,
                                             int nbins, int epb, int E,
                                             const float* __restrict__ W1, ushort_t* __restrict__ Wt1,
                                             const float* __restrict__ W2, ushort_t* __restrict__ Wt2,
                                             const float* __restrict__ W3, ushort_t* __restrict__ Wt3) {
    const int b = blockIdx.x;
    const int t = threadIdx.x;
    if (b < SCAT_NB) {
        __shared__ int h[256];
        h[t] = 0;
        __syncthreads();
        const int base = b * epb;
        const int lim  = min(base + epb, E);
        for (int e = base + t; e < lim; e += 256)
            atomicAdd(&h[eidx[E + e] >> BIN_SHIFT], 1);
        __syncthreads();
        if (t < nbins) bcnt[(size_t)t * SCAT_NB + b] = h[t];
    } else {
        int j = (b - SCAT_NB) * 256 + t;   // W[fin][fout] -> Wt[fout][fin] bf16
        if (j < 128 * 128) {
            int r = j / 128, c = j % 128;
            Wt1[(size_t)c * 128 + r] = f2bf(W1[j]);
        } else if (j < 128 * 128 + 128 * 64) {
            j -= 128 * 128;
            int r = j / 64, c = j % 64;
            Wt2[(size_t)c * 128 + r] = f2bf(W2[j]);
        } else if (j < 128 * 128 + 128 * 64 + 64 * 32) {
            j -= 128 * 128 + 128 * 64;
            int r = j / 32, c = j % 32;
            Wt3[(size_t)c * 64 + r] = f2bf(W3[j]);
        }
    }
}

// ---------------- scans for the bin-offset table ----------------

__global__ __launch_bounds__(256) void k_scan1(const int* __restrict__ cnt,
                                               int* rowptr, int* bsum, int n) {
    __shared__ int tile[256];
    const int t = threadIdx.x;
    const int i = blockIdx.x * 256 + t;
    int v = (i < n) ? cnt[i] : 0;
    tile[t] = v;
    __syncthreads();
    for (int off = 1; off < 256; off <<= 1) {
        int x = (t >= off) ? tile[t - off] : 0;
        __syncthreads();
        tile[t] += x;
        __syncthreads();
    }
    if (i < n) rowptr[i] = tile[t] - v;
    if (t == 255) bsum[blockIdx.x] = tile[255];
}

// single block, arbitrary n (serial tiles with carry), in-place exclusive
__global__ __launch_bounds__(256) void k_scan2x(int* a, int n) {
    __shared__ int tile[256];
    __shared__ int carry_s;
    const int t = threadIdx.x;
    if (t == 0) carry_s = 0;
    __syncthreads();
    for (int base = 0; base < n; base += 256) {
        int i = base + t;
        int v = (i < n) ? a[i] : 0;
        tile[t] = v;
        __syncthreads();
        for (int off = 1; off < 256; off <<= 1) {
            int x = (t >= off) ? tile[t - off] : 0;
            __syncthreads();
            tile[t] += x;
            __syncthreads();
        }
        int carry = carry_s;
        if (i < n) a[i] = carry + tile[t] - v;
        __syncthreads();
        if (t == 255) carry_s = carry + tile[255];
        __syncthreads();
    }
}

// consumers reconstruct global offsets as ebofs[idx] + bsumB[idx>>8]

// ---------------- binned edge scatter (8B packed: (s<<8)|(d&255), w) ----------------

__global__ __launch_bounds__(256) void k_bin_scatter(const int* __restrict__ eidx,
                                                     const float* __restrict__ ea,
                                                     const int* __restrict__ ebofs,
                                                     const int* __restrict__ bsumB,
                                                     uint2* __restrict__ binned,
                                                     int nbins, int epb, int E) {
    __shared__ int h[256];
    __shared__ int lofs[256];
    const int t = threadIdx.x;
    h[t] = 0;
    if (t < nbins) {
        int idx = t * SCAT_NB + blockIdx.x;
        lofs[t] = ebofs[idx] + bsumB[idx >> 8];
    }
    __syncthreads();
    const int base = blockIdx.x * epb;
    const int lim  = min(base + epb, E);
    for (int e = base + t; e < lim; e += 256) {
        int s = eidx[e];
        int d = eidx[E + e];
        float w = ea[e];
        int bin = d >> BIN_SHIFT;
        int r = atomicAdd(&h[bin], 1);      // LDS-local rank
        int pos = lofs[bin] + r;
        binned[pos] = make_uint2(((uint_t)s << 8) | (uint_t)(d & 255), __float_as_uint(w));
    }
}

// ---------------- fused per-bin hist + rowptr + dinv + CSR emit ----------------

__global__ __launch_bounds__(256) void k_bin_finish(const uint2* __restrict__ binned,
                                                    const int* __restrict__ ebofs,
                                                    const int* __restrict__ bsumB,
                                                    float* __restrict__ dinv,
                                                    int* __restrict__ rowptr,
                                                    int* __restrict__ csr_src,
                                                    float* __restrict__ csr_val,
                                                    int nbins, int N, int E) {
    __shared__ uint2 stage[STAGE_CAP];   // 48 KB
    __shared__ ull_t hs[256];
    __shared__ int   sc[256];
    __shared__ int   rp[256];
    __shared__ float dl[256];
    __shared__ int   c2[256];
    const int t = threadIdx.x;
    const int b = blockIdx.x;
    hs[t] = 0ull;
    c2[t] = 0;
    __syncthreads();
    const int i0 = b * SCAT_NB;
    const int start = ebofs[i0] + bsumB[i0 >> 8];
    int end = E;
    if (b + 1 < nbins) {
        int i1 = (b + 1) * SCAT_NB;
        end = ebofs[i1] + bsumB[i1 >> 8];
    }
    const int cnt = end - start;
    const bool fits = (cnt <= STAGE_CAP);

    if (fits) {
        for (int i = t; i < cnt; i += 256) {
            uint2 p = binned[start + i];
            stage[i] = p;
            atomicAdd(&hs[p.x & 255],
                      (1ull << 40) | (ull_t)(__uint_as_float(p.y) * 4294967296.0f));
        }
    } else {
        for (int i = start + t; i < end; i += 256) {
            uint2 p = binned[i];
            atomicAdd(&hs[p.x & 255],
                      (1ull << 40) | (ull_t)(__uint_as_float(p.y) * 4294967296.0f));
        }
    }
    __syncthreads();

    int v = (int)(hs[t] >> 40);
    sc[t] = v;
    __syncthreads();
    for (int off = 1; off < 256; off <<= 1) {
        int x = (t >= off) ? sc[t - off] : 0;
        __syncthreads();
        sc[t] += x;
        __syncthreads();
    }
    {
        ull_t s = hs[t];
        float dg = 1.0f + (float)(s & ((1ull << 40) - 1)) * (1.0f / 4294967296.0f);
        float di = rsqrtf(dg);
        dl[t] = di;
        rp[t] = start + sc[t] - v;
        const int node = (b << BIN_SHIFT) + t;
        if (node < N) {
            dinv[node]   = di;
            rowptr[node] = rp[t];
        }
        if (b == 0 && t == 0) rowptr[N] = E;
    }
    __syncthreads();

    if (fits) {
        for (int i = t; i < cnt; i += 256) {
            uint2 p = stage[i];
            int d8 = p.x & 255;
            int r = atomicAdd(&c2[d8], 1);
            int pos = rp[d8] + r;
            csr_src[pos] = (int)(p.x >> 8);
            csr_val[pos] = __uint_as_float(p.y) * dl[d8];
        }
    } else {
        for (int i = start + t; i < end; i += 256) {
            uint2 p = binned[i];
            int d8 = p.x & 255;
            int r = atomicAdd(&c2[d8], 1);
            int pos = rp[d8] + r;
            csr_src[pos] = (int)(p.x >> 8);
            csr_val[pos] = __uint_as_float(p.y) * dl[d8];
        }
    }
}

// ---------------- gather-accumulate body (ushort8 = 16B/lane, single-stream x8) ----

#define ACC8(vj, mj)                                                              \
    { a[0] += vj * bf2f(mj[0]); a[1] += vj * bf2f(mj[1]);                         \
      a[2] += vj * bf2f(mj[2]); a[3] += vj * bf2f(mj[3]);                         \
      a[4] += vj * bf2f(mj[4]); a[5] += vj * bf2f(mj[5]);                         \
      a[6] += vj * bf2f(mj[6]); a[7] += vj * bf2f(mj[7]); }

template <int FIN>
static __device__ __forceinline__ void agg_body(const ushort_t* __restrict__ Hf,
                                                const int* __restrict__ csr_src,
                                                const float* __restrict__ csr_val,
                                                int e0, int e1, float* a /*[8]*/) {
    int e = e0;
    for (; e + 8 <= e1; e += 8) {
        int   s0 = csr_src[e+0], s1 = csr_src[e+1], s2 = csr_src[e+2], s3 = csr_src[e+3];
        int   s4 = csr_src[e+4], s5 = csr_src[e+5], s6 = csr_src[e+6], s7 = csr_src[e+7];
        float v0 = csr_val[e+0], v1 = csr_val[e+1], v2 = csr_val[e+2], v3 = csr_val[e+3];
        float v4 = csr_val[e+4], v5 = csr_val[e+5], v6 = csr_val[e+6], v7 = csr_val[e+7];
        ushort8_t m0 = *(const ushort8_t*)(Hf + (size_t)s0 * FIN);
        ushort8_t m1 = *(const ushort8_t*)(Hf + (size_t)s1 * FIN);
        ushort8_t m2 = *(const ushort8_t*)(Hf + (size_t)s2 * FIN);
        ushort8_t m3 = *(const ushort8_t*)(Hf + (size_t)s3 * FIN);
        ushort8_t m4 = *(const ushort8_t*)(Hf + (size_t)s4 * FIN);
        ushort8_t m5 = *(const ushort8_t*)(Hf + (size_t)s5 * FIN);
        ushort8_t m6 = *(const ushort8_t*)(Hf + (size_t)s6 * FIN);
        ushort8_t m7 = *(const ushort8_t*)(Hf + (size_t)s7 * FIN);
        ACC8(v0, m0); ACC8(v1, m1); ACC8(v2, m2); ACC8(v3, m3);
        ACC8(v4, m4); ACC8(v5, m5); ACC8(v6, m6); ACC8(v7, m7);
    }
    for (; e + 2 <= e1; e += 2) {
        int   s0 = csr_src[e+0], s1 = csr_src[e+1];
        float v0 = csr_val[e+0], v1 = csr_val[e+1];
        ushort8_t m0 = *(const ushort8_t*)(Hf + (size_t)s0 * FIN);
        ushort8_t m1 = *(const ushort8_t*)(Hf + (size_t)s1 * FIN);
        ACC8(v0, m0); ACC8(v1, m1);
    }
    if (e < e1) {
        int   s0 = csr_src[e];
        float v0 = csr_val[e];
        ushort8_t m0 = *(const ushort8_t*)(Hf + (size_t)s0 * FIN);
        ACC8(v0, m0);
    }
}

// ---------------- FUSED agg + gemm: G = relu(agg(H')+b); C = dinv*(G @ Wt^T) ----------------
// Phase A: block aggregates 32 nodes (ushort8 gathers) -> bf16 LDS tile.
// Phase B: 4 waves MFMA the tile vs Wt, epilogue row-scales by dinv.

template <int FIN, int FOUT>
__global__ __launch_bounds__(256) void k_agg_gemm(const ushort_t* __restrict__ H,
                                                  const float* __restrict__ dinv,
                                                  const int* __restrict__ rowptr,
                                                  const int* __restrict__ csr_src,
                                                  const float* __restrict__ csr_val,
                                                  const float* __restrict__ bias,
                                                  const ushort_t* __restrict__ Wt,
                                                  ushort_t* __restrict__ C, int n) {
    constexpr int PAD = 8;
    __shared__ ushort_t Gs[32][FIN + PAD];
    constexpr int LPN = FIN / 8;       // lanes per node: 16 / 8
    constexpr int NPW = 64 / LPN;      // nodes per wave: 4 / 8
    constexpr int NPB = NPW * 4;       // nodes per block pass: 16 / 32
    constexpr int NPASS = 32 / NPB;    // 2 / 1
    constexpr int NT = FOUT / 16;      // col tiles: 4 / 2
    constexpr int NK = FIN / 32;       // K steps: 4 / 2

    const int wave = threadIdx.x >> 6;
    const int lane = threadIdx.x & 63;
    const int r0 = blockIdx.x * 32;
    const int sub = lane / LPN;
    const int f8  = lane % LPN;
    const ushort_t* __restrict__ Hf = H + 8 * f8;

    // ---- phase A: aggregate 32 nodes into LDS ----
#pragma unroll
    for (int p = 0; p < NPASS; ++p) {
        const int nb = p * NPB + wave * NPW + sub;
        const int node = r0 + nb;
        float a[8] = {};
        if (node < n) {
            const float sn = dinv[node];
            ushort8_t hv = *(const ushort8_t*)(Hf + (size_t)node * FIN);
#pragma unroll
            for (int k = 0; k < 8; ++k) a[k] = sn * bf2f(hv[k]);
            agg_body<FIN>(Hf, csr_src, csr_val, rowptr[node], rowptr[node + 1], a);
            float4 bv0 = *(const float4*)(bias + 8 * f8);
            float4 bv1 = *(const float4*)(bias + 8 * f8 + 4);
            a[0] = fmaxf(a[0] + bv0.x, 0.f); a[1] = fmaxf(a[1] + bv0.y, 0.f);
            a[2] = fmaxf(a[2] + bv0.z, 0.f); a[3] = fmaxf(a[3] + bv0.w, 0.f);
            a[4] = fmaxf(a[4] + bv1.x, 0.f); a[5] = fmaxf(a[5] + bv1.y, 0.f);
            a[6] = fmaxf(a[6] + bv1.z, 0.f); a[7] = fmaxf(a[7] + bv1.w, 0.f);
        }
        ushort8_t o;
#pragma unroll
        for (int k = 0; k < 8; ++k) o[k] = f2bf(a[k]);
        *(ushort8_t*)(&Gs[nb][8 * f8]) = o;
    }
    __syncthreads();

    // ---- phase B: 32-row MFMA from LDS ----
    const int l15 = lane & 15;
    const int kg  = lane >> 4;
    for (int item = wave; item < 2 * NT; item += 4) {
        const int g  = item / NT;      // row group
        const int ct = item % NT;      // col tile
        f32x4 acc = (f32x4)(0.0f);
        const ushort_t* Bp = Wt + (size_t)(ct * 16 + l15) * FIN + kg * 8;
        const int arow = g * 16 + l15;
#pragma unroll
        for (int ks = 0; ks < NK; ++ks) {
            bf16x8 a = *(const bf16x8*)(&Gs[arow][kg * 8 + ks * 32]);
            bf16x8 b = *(const bf16x8*)(Bp + ks * 32);
            acc = __builtin_amdgcn_mfma_f32_16x16x32_bf16(a, b, acc, 0, 0, 0);
        }
        const int rbase = r0 + g * 16 + kg * 4;
#pragma unroll
        for (int j = 0; j < 4; ++j) {
            int row = rbase + j;
            if (row < n)
                C[(size_t)row * FOUT + ct * 16 + l15] = f2bf(acc[j] * dinv[row]);
        }
    }
}

// ---------------- MFMA GEMM (layer 1): C = dinv * (x(f32) @ Wt^T) ----------------

template <int FIN, int FOUT>
__global__ __launch_bounds__(256) void k_gemm_f32(const float* __restrict__ A,
                                                  const ushort_t* __restrict__ Wt,
                                                  const float* __restrict__ dinv,
                                                  ushort_t* __restrict__ C, int n) {
    constexpr int NT = FOUT / 16;
    constexpr int NK = FIN / 32;
    const int wave = threadIdx.x >> 6;
    const int lane = threadIdx.x & 63;
    const int r0 = (blockIdx.x * 4 + wave) * 32;
    if (r0 >= n) return;

    const int l15 = lane & 15;
    const int kg  = lane >> 4;
    const int arow0 = min(r0 + l15, n - 1);
    const int arow1 = min(r0 + 16 + l15, n - 1);

    f32x4 acc0[NT], acc1[NT];
#pragma unroll
    for (int c = 0; c < NT; ++c) { acc0[c] = (f32x4)(0.0f); acc1[c] = (f32x4)(0.0f); }

    const ushort_t* Bp = Wt + (size_t)l15 * FIN + kg * 8;

#pragma unroll 1   // keep rolled: full unroll hoists all B loads -> spill (R1 lesson)
    for (int ks = 0; ks < NK; ++ks) {
        bf16x8 a0, a1;
        const float* p0 = A + (size_t)arow0 * FIN + kg * 8 + ks * 32;
        const float* p1 = A + (size_t)arow1 * FIN + kg * 8 + ks * 32;
        float4 u0 = *(const float4*)p0, u1 = *(const float4*)(p0 + 4);
        float4 w0 = *(const float4*)p1, w1 = *(const float4*)(p1 + 4);
        a0[0] = (short)f2bf(u0.x); a0[1] = (short)f2bf(u0.y);
        a0[2] = (short)f2bf(u0.z); a0[3] = (short)f2bf(u0.w);
        a0[4] = (short)f2bf(u1.x); a0[5] = (short)f2bf(u1.y);
        a0[6] = (short)f2bf(u1.z); a0[7] = (short)f2bf(u1.w);
        a1[0] = (short)f2bf(w0.x); a1[1] = (short)f2bf(w0.y);
        a1[2] = (short)f2bf(w0.z); a1[3] = (short)f2bf(w0.w);
        a1[4] = (short)f2bf(w1.x); a1[5] = (short)f2bf(w1.y);
        a1[6] = (short)f2bf(w1.z); a1[7] = (short)f2bf(w1.w);
#pragma unroll
        for (int c = 0; c < NT; ++c) {
            bf16x8 bfr = *(const bf16x8*)(Bp + (size_t)c * 16 * FIN + ks * 32);
            acc0[c] = __builtin_amdgcn_mfma_f32_16x16x32_bf16(a0, bfr, acc0[c], 0, 0, 0);
            acc1[c] = __builtin_amdgcn_mfma_f32_16x16x32_bf16(a1, bfr, acc1[c], 0, 0, 0);
        }
    }

#pragma unroll
    for (int g = 0; g < 2; ++g) {
        const int rbase = r0 + g * 16 + kg * 4;
#pragma unroll
        for (int j = 0; j < 4; ++j) {
            int row = rbase + j;
            if (row < n) {
                float dscale = dinv[row];
#pragma unroll
                for (int c = 0; c < NT; ++c) {
                    float val = (g == 0) ? acc0[c][j] : acc1[c][j];
                    C[(size_t)row * FOUT + c * 16 + l15] = f2bf(val * dscale);
                }
            }
        }
    }
}

// ---------------- final aggregation (layer 3, f32 out, no relu) ----------------

template <int FIN>
__global__ __launch_bounds__(256) void k_agg_final(const ushort_t* __restrict__ H,
                                                   const float* __restrict__ dinv,
                                                   const int* __restrict__ rowptr,
                                                   const int* __restrict__ csr_src,
                                                   const float* __restrict__ csr_val,
                                                   const float* __restrict__ bias,
                                                   float* __restrict__ out, int n) {
    constexpr int LPN = FIN / 8;       // 4 lanes per node
    constexpr int NPW = 64 / LPN;      // 16 nodes per wave
    const int wave = threadIdx.x >> 6;
    const int lane = threadIdx.x & 63;
    const int sub  = lane / LPN;
    const int f8   = lane % LPN;
    const int node = (blockIdx.x * 4 + wave) * NPW + sub;
    if (node >= n) return;

    const ushort_t* __restrict__ Hf = H + 8 * f8;
    const float sn = dinv[node];
    ushort8_t hv = *(const ushort8_t*)(Hf + (size_t)node * FIN);
    float a[8];
#pragma unroll
    for (int k = 0; k < 8; ++k) a[k] = sn * bf2f(hv[k]);

    agg_body<FIN>(Hf, csr_src, csr_val, rowptr[node], rowptr[node + 1], a);

    float4 bv0 = *(const float4*)(bias + 8 * f8);
    float4 bv1 = *(const float4*)(bias + 8 * f8 + 4);
    a[0] += bv0.x; a[1] += bv0.y; a[2] += bv0.z; a[3] += bv0.w;
    a[4] += bv1.x; a[5] += bv1.y; a[6] += bv1.z; a[7] += bv1.w;
    float* op = out + (size_t)node * FIN + 8 * f8;
    *(float4*)op       = make_float4(a[0], a[1], a[2], a[3]);
    *(float4*)(op + 4) = make_float4(a[4], a[5], a[6], a[7]);
}

// ---------------- launch ----------------

extern "C" void kernel_launch(void* const* d_in, const int* in_sizes, int n_in,
                              void* d_out, int out_size, void* d_ws, size_t ws_size,
                              hipStream_t stream) {
    const float* x    = (const float*)d_in[0];
    const int*   eidx = (const int*)d_in[1];
    const float* ea   = (const float*)d_in[2];
    const float* W1   = (const float*)d_in[3];
    const float* b1   = (const float*)d_in[4];
    const float* W2   = (const float*)d_in[5];
    const float* b2   = (const float*)d_in[6];
    const float* W3   = (const float*)d_in[7];
    const float* b3   = (const float*)d_in[8];

    const int N = in_sizes[0] / 128;
    const int E = in_sizes[2];

    const int nbins = (N + 255) >> BIN_SHIFT;            // 196 for N=50000 (<=256)
    const int epb   = (E + SCAT_NB - 1) / SCAT_NB;       // edges per scatter block
    const int nbc   = nbins * SCAT_NB;                   // bcnt/ebofs length
    const int gBC   = (nbc + BLK - 1) / BLK;

    char*  base = (char*)d_ws;
    size_t off  = 0;
    auto carve = [&](size_t nbytes) -> void* {
        void* p = base + off;
        off = (off + nbytes + 255) & ~(size_t)255;
        return p;
    };
    int*   bcnt      = (int*)  carve((size_t)nbc * 4);
    int*   ebofs     = (int*)  carve((size_t)nbc * 4);
    int*   bsumB     = (int*)  carve((size_t)512 * 4);
    uint2* binned    = (uint2*)carve((size_t)E * 8);
    float* dinv      = (float*)carve((size_t)N * 4);
    int*   rowptr    = (int*)  carve((size_t)(N + 1) * 4);
    int*   csr_src   = (int*)  carve((size_t)E * 4);
    float* csr_val   = (float*)carve((size_t)E * 4);
    ushort_t* bufA   = (ushort_t*)carve((size_t)N * 128 * 2);   // bf16: H'1 / H'3
    ushort_t* bufB   = (ushort_t*)carve((size_t)N * 64 * 2);    // bf16: H'2
    ushort_t* Wt1    = (ushort_t*)carve((size_t)128 * 128 * 2);
    ushort_t* Wt2    = (ushort_t*)carve((size_t)64 * 128 * 2);
    ushort_t* Wt3    = (ushort_t*)carve((size_t)32 * 64 * 2);
    (void)ws_size;

    const int wtot = 128 * 128 + 128 * 64 + 64 * 32;
    const int gPre = SCAT_NB + (wtot + 255) / 256;
    const int gR  = (N + 127) / 128;                     // gemm1 blocks (128 rows/block)
    const int gF  = (N + 31) / 32;                       // fused agg+gemm blocks (32 rows)

    // preprocessing (5 dispatches, scan-based, no global atomics)
    k_pre<<<gPre, BLK, 0, stream>>>(eidx, bcnt, nbins, epb, E, W1, Wt1, W2, Wt2, W3, Wt3);
    k_scan1<<<gBC, BLK, 0, stream>>>(bcnt, ebofs, bsumB, nbc);
    k_scan2x<<<1, BLK, 0, stream>>>(bsumB, gBC);
    k_bin_scatter<<<SCAT_NB, BLK, 0, stream>>>(eidx, ea, ebofs, bsumB, binned, nbins, epb, E);
    k_bin_finish<<<nbins, BLK, 0, stream>>>(binned, ebofs, bsumB, dinv, rowptr,
                                            csr_src, csr_val, nbins, N, E);

    // layer 1 GEMM: H'1 = dinv * (x @ W1)   (reads f32 x directly)
    k_gemm_f32<128, 128><<<gR, BLK, 0, stream>>>(x, Wt1, dinv, bufA, N);

    // fused: G2 = relu(agg(H'1)+b1); H'2 = dinv*(G2 @ W2)
    k_agg_gemm<128, 64><<<gF, BLK, 0, stream>>>(bufA, dinv, rowptr, csr_src, csr_val,
                                                b1, Wt2, bufB, N);

    // fused: G3 = relu(agg(H'2)+b2); H'3 = dinv*(G3 @ W3)
    k_agg_gemm<64, 32><<<gF, BLK, 0, stream>>>(bufB, dinv, rowptr, csr_src, csr_val,
                                               b2, Wt3, bufA, N);

    // final: out = agg(H'3) + b3   (f32, no relu)
    k_agg_final<32><<<(N + 63) / 64, BLK, 0, stream>>>(bufA, dinv, rowptr, csr_src, csr_val,
                                                       b3, (float*)d_out, N);
}

// Round 19
// 129.971 us; speedup vs baseline: 1.2373x; 1.0177x over previous
//
#include <hip/hip_runtime.h>
#include <hip/hip_bf16.h>

#define BLK 256
#define SCAT_NB 512        // blocks in the binning scatter pass
#define BIN_SHIFT 8        // 256 nodes per bin
#define STAGE_CAP 6144     // LDS-staged edges per bin (mean ~4080, 19-sigma headroom)

typedef unsigned short ushort_t;
typedef unsigned int uint_t;
typedef unsigned long long ull_t;
typedef __attribute__((ext_vector_type(8))) short bf16x8;
typedef __attribute__((ext_vector_type(8))) unsigned short ushort8_t;
typedef __attribute__((ext_vector_type(4))) float f32x4;

static __device__ __forceinline__ float bf2f(ushort_t u) {
    return __uint_as_float((uint_t)u << 16);
}
static __device__ __forceinline__ ushort_t f2bf(float f) {
    __hip_bfloat16 h = __float2bfloat16(f);   // RNE
    return *reinterpret_cast<ushort_t*>(&h);
}

// ================= structure (R18) =================
// R18 counters: fused agg+gemm 44.5us, VGPR 52, latency-stall bound. Each 8-edge
// batch = 2 serial round trips (csr_src loads -> dependent H gathers). R19:
// software-pipeline ONLY the src-index stream (prefetch next batch's s[8], +8
// VGPR, stays in the <=64-VGPR occupancy bucket; R17's failure was crossing it).

// ---------------- fused prologue: bin_count + weight conv ----------------

__global__ __launch_bounds__(256) void k_pre(const int* __restrict__ eidx,
                                             int* __restrict__ bcnt,
                                             int nbins, int epb, int E,
                                             const float* __restrict__ W1, ushort_t* __restrict__ Wt1,
                                             const float* __restrict__ W2, ushort_t* __restrict__ Wt2,
                                             const float* __restrict__ W3, ushort_t* __restrict__ Wt3) {
    const int b = blockIdx.x;
    const int t = threadIdx.x;
    if (b < SCAT_NB) {
        __shared__ int h[256];
        h[t] = 0;
        __syncthreads();
        const int base = b * epb;
        const int lim  = min(base + epb, E);
        for (int e = base + t; e < lim; e += 256)
            atomicAdd(&h[eidx[E + e] >> BIN_SHIFT], 1);
        __syncthreads();
        if (t < nbins) bcnt[(size_t)t * SCAT_NB + b] = h[t];
    } else {
        int j = (b - SCAT_NB) * 256 + t;   // W[fin][fout] -> Wt[fout][fin] bf16
        if (j < 128 * 128) {
            int r = j / 128, c = j % 128;
            Wt1[(size_t)c * 128 + r] = f2bf(W1[j]);
        } else if (j < 128 * 128 + 128 * 64) {
            j -= 128 * 128;
            int r = j / 64, c = j % 64;
            Wt2[(size_t)c * 128 + r] = f2bf(W2[j]);
        } else if (j < 128 * 128 + 128 * 64 + 64 * 32) {
            j -= 128 * 128 + 128 * 64;
            int r = j / 32, c = j % 32;
            Wt3[(size_t)c * 64 + r] = f2bf(W3[j]);
        }
    }
}

// ---------------- scans for the bin-offset table ----------------

__global__ __launch_bounds__(256) void k_scan1(const int* __restrict__ cnt,
                                               int* rowptr, int* bsum, int n) {
    __shared__ int tile[256];
    const int t = threadIdx.x;
    const int i = blockIdx.x * 256 + t;
    int v = (i < n) ? cnt[i] : 0;
    tile[t] = v;
    __syncthreads();
    for (int off = 1; off < 256; off <<= 1) {
        int x = (t >= off) ? tile[t - off] : 0;
        __syncthreads();
        tile[t] += x;
        __syncthreads();
    }
    if (i < n) rowptr[i] = tile[t] - v;
    if (t == 255) bsum[blockIdx.x] = tile[255];
}

// single block, arbitrary n (serial tiles with carry), in-place exclusive
__global__ __launch_bounds__(256) void k_scan2x(int* a, int n) {
    __shared__ int tile[256];
    __shared__ int carry_s;
    const int t = threadIdx.x;
    if (t == 0) carry_s = 0;
    __syncthreads();
    for (int base = 0; base < n; base += 256) {
        int i = base + t;
        int v = (i < n) ? a[i] : 0;
        tile[t] = v;
        __syncthreads();
        for (int off = 1; off < 256; off <<= 1) {
            int x = (t >= off) ? tile[t - off] : 0;
            __syncthreads();
            tile[t] += x;
            __syncthreads();
        }
        int carry = carry_s;
        if (i < n) a[i] = carry + tile[t] - v;
        __syncthreads();
        if (t == 255) carry_s = carry + tile[255];
        __syncthreads();
    }
}

// consumers reconstruct global offsets as ebofs[idx] + bsumB[idx>>8]

// ---------------- binned edge scatter (8B packed: (s<<8)|(d&255), w) ----------------

__global__ __launch_bounds__(256) void k_bin_scatter(const int* __restrict__ eidx,
                                                     const float* __restrict__ ea,
                                                     const int* __restrict__ ebofs,
                                                     const int* __restrict__ bsumB,
                                                     uint2* __restrict__ binned,
                                                     int nbins, int epb, int E) {
    __shared__ int h[256];
    __shared__ int lofs[256];
    const int t = threadIdx.x;
    h[t] = 0;
    if (t < nbins) {
        int idx = t * SCAT_NB + blockIdx.x;
        lofs[t] = ebofs[idx] + bsumB[idx >> 8];
    }
    __syncthreads();
    const int base = blockIdx.x * epb;
    const int lim  = min(base + epb, E);
    for (int e = base + t; e < lim; e += 256) {
        int s = eidx[e];
        int d = eidx[E + e];
        float w = ea[e];
        int bin = d >> BIN_SHIFT;
        int r = atomicAdd(&h[bin], 1);      // LDS-local rank
        int pos = lofs[bin] + r;
        binned[pos] = make_uint2(((uint_t)s << 8) | (uint_t)(d & 255), __float_as_uint(w));
    }
}

// ---------------- fused per-bin hist + rowptr + dinv + CSR emit ----------------

__global__ __launch_bounds__(256) void k_bin_finish(const uint2* __restrict__ binned,
                                                    const int* __restrict__ ebofs,
                                                    const int* __restrict__ bsumB,
                                                    float* __restrict__ dinv,
                                                    int* __restrict__ rowptr,
                                                    int* __restrict__ csr_src,
                                                    float* __restrict__ csr_val,
                                                    int nbins, int N, int E) {
    __shared__ uint2 stage[STAGE_CAP];   // 48 KB
    __shared__ ull_t hs[256];
    __shared__ int   sc[256];
    __shared__ int   rp[256];
    __shared__ float dl[256];
    __shared__ int   c2[256];
    const int t = threadIdx.x;
    const int b = blockIdx.x;
    hs[t] = 0ull;
    c2[t] = 0;
    __syncthreads();
    const int i0 = b * SCAT_NB;
    const int start = ebofs[i0] + bsumB[i0 >> 8];
    int end = E;
    if (b + 1 < nbins) {
        int i1 = (b + 1) * SCAT_NB;
        end = ebofs[i1] + bsumB[i1 >> 8];
    }
    const int cnt = end - start;
    const bool fits = (cnt <= STAGE_CAP);

    if (fits) {
        for (int i = t; i < cnt; i += 256) {
            uint2 p = binned[start + i];
            stage[i] = p;
            atomicAdd(&hs[p.x & 255],
                      (1ull << 40) | (ull_t)(__uint_as_float(p.y) * 4294967296.0f));
        }
    } else {
        for (int i = start + t; i < end; i += 256) {
            uint2 p = binned[i];
            atomicAdd(&hs[p.x & 255],
                      (1ull << 40) | (ull_t)(__uint_as_float(p.y) * 4294967296.0f));
        }
    }
    __syncthreads();

    int v = (int)(hs[t] >> 40);
    sc[t] = v;
    __syncthreads();
    for (int off = 1; off < 256; off <<= 1) {
        int x = (t >= off) ? sc[t - off] : 0;
        __syncthreads();
        sc[t] += x;
        __syncthreads();
    }
    {
        ull_t s = hs[t];
        float dg = 1.0f + (float)(s & ((1ull << 40) - 1)) * (1.0f / 4294967296.0f);
        float di = rsqrtf(dg);
        dl[t] = di;
        rp[t] = start + sc[t] - v;
        const int node = (b << BIN_SHIFT) + t;
        if (node < N) {
            dinv[node]   = di;
            rowptr[node] = rp[t];
        }
        if (b == 0 && t == 0) rowptr[N] = E;
    }
    __syncthreads();

    if (fits) {
        for (int i = t; i < cnt; i += 256) {
            uint2 p = stage[i];
            int d8 = p.x & 255;
            int r = atomicAdd(&c2[d8], 1);
            int pos = rp[d8] + r;
            csr_src[pos] = (int)(p.x >> 8);
            csr_val[pos] = __uint_as_float(p.y) * dl[d8];
        }
    } else {
        for (int i = start + t; i < end; i += 256) {
            uint2 p = binned[i];
            int d8 = p.x & 255;
            int r = atomicAdd(&c2[d8], 1);
            int pos = rp[d8] + r;
            csr_src[pos] = (int)(p.x >> 8);
            csr_val[pos] = __uint_as_float(p.y) * dl[d8];
        }
    }
}

// ---------------- gather-accumulate body (ushort8 + src-index software pipeline) ----

#define ACC8(vj, mj)                                                              \
    { a[0] += vj * bf2f(mj[0]); a[1] += vj * bf2f(mj[1]);                         \
      a[2] += vj * bf2f(mj[2]); a[3] += vj * bf2f(mj[3]);                         \
      a[4] += vj * bf2f(mj[4]); a[5] += vj * bf2f(mj[5]);                         \
      a[6] += vj * bf2f(mj[6]); a[7] += vj * bf2f(mj[7]); }

template <int FIN>
static __device__ __forceinline__ void agg_body(const ushort_t* __restrict__ Hf,
                                                const int* __restrict__ csr_src,
                                                const float* __restrict__ csr_val,
                                                int e0, int e1, float* a /*[8]*/) {
    int e = e0;
    const int nb = (e1 - e0) >> 3;
    if (nb > 0) {
        // prime: src indices of batch 0 in flight
        int s0 = csr_src[e+0], s1 = csr_src[e+1], s2 = csr_src[e+2], s3 = csr_src[e+3];
        int s4 = csr_src[e+4], s5 = csr_src[e+5], s6 = csr_src[e+6], s7 = csr_src[e+7];
        for (int b = 1; b < nb; ++b) {
            const int en = e + 8;
            // prefetch NEXT batch's src indices (hides the index round-trip)
            int t0 = csr_src[en+0], t1 = csr_src[en+1], t2 = csr_src[en+2], t3 = csr_src[en+3];
            int t4 = csr_src[en+4], t5 = csr_src[en+5], t6 = csr_src[en+6], t7 = csr_src[en+7];
            ushort8_t m0 = *(const ushort8_t*)(Hf + (size_t)s0 * FIN);
            ushort8_t m1 = *(const ushort8_t*)(Hf + (size_t)s1 * FIN);
            ushort8_t m2 = *(const ushort8_t*)(Hf + (size_t)s2 * FIN);
            ushort8_t m3 = *(const ushort8_t*)(Hf + (size_t)s3 * FIN);
            ushort8_t m4 = *(const ushort8_t*)(Hf + (size_t)s4 * FIN);
            ushort8_t m5 = *(const ushort8_t*)(Hf + (size_t)s5 * FIN);
            ushort8_t m6 = *(const ushort8_t*)(Hf + (size_t)s6 * FIN);
            ushort8_t m7 = *(const ushort8_t*)(Hf + (size_t)s7 * FIN);
            float v0 = csr_val[e+0], v1 = csr_val[e+1], v2 = csr_val[e+2], v3 = csr_val[e+3];
            float v4 = csr_val[e+4], v5 = csr_val[e+5], v6 = csr_val[e+6], v7 = csr_val[e+7];
            ACC8(v0, m0); ACC8(v1, m1); ACC8(v2, m2); ACC8(v3, m3);
            ACC8(v4, m4); ACC8(v5, m5); ACC8(v6, m6); ACC8(v7, m7);
            s0 = t0; s1 = t1; s2 = t2; s3 = t3;
            s4 = t4; s5 = t5; s6 = t6; s7 = t7;
            e = en;
        }
        {   // drain batch
            ushort8_t m0 = *(const ushort8_t*)(Hf + (size_t)s0 * FIN);
            ushort8_t m1 = *(const ushort8_t*)(Hf + (size_t)s1 * FIN);
            ushort8_t m2 = *(const ushort8_t*)(Hf + (size_t)s2 * FIN);
            ushort8_t m3 = *(const ushort8_t*)(Hf + (size_t)s3 * FIN);
            ushort8_t m4 = *(const ushort8_t*)(Hf + (size_t)s4 * FIN);
            ushort8_t m5 = *(const ushort8_t*)(Hf + (size_t)s5 * FIN);
            ushort8_t m6 = *(const ushort8_t*)(Hf + (size_t)s6 * FIN);
            ushort8_t m7 = *(const ushort8_t*)(Hf + (size_t)s7 * FIN);
            float v0 = csr_val[e+0], v1 = csr_val[e+1], v2 = csr_val[e+2], v3 = csr_val[e+3];
            float v4 = csr_val[e+4], v5 = csr_val[e+5], v6 = csr_val[e+6], v7 = csr_val[e+7];
            ACC8(v0, m0); ACC8(v1, m1); ACC8(v2, m2); ACC8(v3, m3);
            ACC8(v4, m4); ACC8(v5, m5); ACC8(v6, m6); ACC8(v7, m7);
            e += 8;
        }
    }
    for (; e + 2 <= e1; e += 2) {
        int   s0 = csr_src[e+0], s1 = csr_src[e+1];
        float v0 = csr_val[e+0], v1 = csr_val[e+1];
        ushort8_t m0 = *(const ushort8_t*)(Hf + (size_t)s0 * FIN);
        ushort8_t m1 = *(const ushort8_t*)(Hf + (size_t)s1 * FIN);
        ACC8(v0, m0); ACC8(v1, m1);
    }
    if (e < e1) {
        int   s0 = csr_src[e];
        float v0 = csr_val[e];
        ushort8_t m0 = *(const ushort8_t*)(Hf + (size_t)s0 * FIN);
        ACC8(v0, m0);
    }
}

// ---------------- FUSED agg + gemm: G = relu(agg(H')+b); C = dinv*(G @ Wt^T) ----------------

template <int FIN, int FOUT>
__global__ __launch_bounds__(256) void k_agg_gemm(const ushort_t* __restrict__ H,
                                                  const float* __restrict__ dinv,
                                                  const int* __restrict__ rowptr,
                                                  const int* __restrict__ csr_src,
                                                  const float* __restrict__ csr_val,
                                                  const float* __restrict__ bias,
                                                  const ushort_t* __restrict__ Wt,
                                                  ushort_t* __restrict__ C, int n) {
    constexpr int PAD = 8;
    __shared__ ushort_t Gs[32][FIN + PAD];
    constexpr int LPN = FIN / 8;       // lanes per node: 16 / 8
    constexpr int NPW = 64 / LPN;      // nodes per wave: 4 / 8
    constexpr int NPB = NPW * 4;       // nodes per block pass: 16 / 32
    constexpr int NPASS = 32 / NPB;    // 2 / 1
    constexpr int NT = FOUT / 16;      // col tiles: 4 / 2
    constexpr int NK = FIN / 32;       // K steps: 4 / 2

    const int wave = threadIdx.x >> 6;
    const int lane = threadIdx.x & 63;
    const int r0 = blockIdx.x * 32;
    const int sub = lane / LPN;
    const int f8  = lane % LPN;
    const ushort_t* __restrict__ Hf = H + 8 * f8;

    // ---- phase A: aggregate 32 nodes into LDS ----
#pragma unroll
    for (int p = 0; p < NPASS; ++p) {
        const int nb = p * NPB + wave * NPW + sub;
        const int node = r0 + nb;
        float a[8] = {};
        if (node < n) {
            const float sn = dinv[node];
            ushort8_t hv = *(const ushort8_t*)(Hf + (size_t)node * FIN);
#pragma unroll
            for (int k = 0; k < 8; ++k) a[k] = sn * bf2f(hv[k]);
            agg_body<FIN>(Hf, csr_src, csr_val, rowptr[node], rowptr[node + 1], a);
            float4 bv0 = *(const float4*)(bias + 8 * f8);
            float4 bv1 = *(const float4*)(bias + 8 * f8 + 4);
            a[0] = fmaxf(a[0] + bv0.x, 0.f); a[1] = fmaxf(a[1] + bv0.y, 0.f);
            a[2] = fmaxf(a[2] + bv0.z, 0.f); a[3] = fmaxf(a[3] + bv0.w, 0.f);
            a[4] = fmaxf(a[4] + bv1.x, 0.f); a[5] = fmaxf(a[5] + bv1.y, 0.f);
            a[6] = fmaxf(a[6] + bv1.z, 0.f); a[7] = fmaxf(a[7] + bv1.w, 0.f);
        }
        ushort8_t o;
#pragma unroll
        for (int k = 0; k < 8; ++k) o[k] = f2bf(a[k]);
        *(ushort8_t*)(&Gs[nb][8 * f8]) = o;
    }
    __syncthreads();

    // ---- phase B: 32-row MFMA from LDS ----
    const int l15 = lane & 15;
    const int kg  = lane >> 4;
    for (int item = wave; item < 2 * NT; item += 4) {
        const int g  = item / NT;      // row group
        const int ct = item % NT;      // col tile
        f32x4 acc = (f32x4)(0.0f);
        const ushort_t* Bp = Wt + (size_t)(ct * 16 + l15) * FIN + kg * 8;
        const int arow = g * 16 + l15;
#pragma unroll
        for (int ks = 0; ks < NK; ++ks) {
            bf16x8 a = *(const bf16x8*)(&Gs[arow][kg * 8 + ks * 32]);
            bf16x8 b = *(const bf16x8*)(Bp + ks * 32);
            acc = __builtin_amdgcn_mfma_f32_16x16x32_bf16(a, b, acc, 0, 0, 0);
        }
        const int rbase = r0 + g * 16 + kg * 4;
#pragma unroll
        for (int j = 0; j < 4; ++j) {
            int row = rbase + j;
            if (row < n)
                C[(size_t)row * FOUT + ct * 16 + l15] = f2bf(acc[j] * dinv[row]);
        }
    }
}

// ---------------- MFMA GEMM (layer 1): C = dinv * (x(f32) @ Wt^T) ----------------

template <int FIN, int FOUT>
__global__ __launch_bounds__(256) void k_gemm_f32(const float* __restrict__ A,
                                                  const ushort_t* __restrict__ Wt,
                                                  const float* __restrict__ dinv,
                                                  ushort_t* __restrict__ C, int n) {
    constexpr int NT = FOUT / 16;
    constexpr int NK = FIN / 32;
    const int wave = threadIdx.x >> 6;
    const int lane = threadIdx.x & 63;
    const int r0 = (blockIdx.x * 4 + wave) * 32;
    if (r0 >= n) return;

    const int l15 = lane & 15;
    const int kg  = lane >> 4;
    const int arow0 = min(r0 + l15, n - 1);
    const int arow1 = min(r0 + 16 + l15, n - 1);

    f32x4 acc0[NT], acc1[NT];
#pragma unroll
    for (int c = 0; c < NT; ++c) { acc0[c] = (f32x4)(0.0f); acc1[c] = (f32x4)(0.0f); }

    const ushort_t* Bp = Wt + (size_t)l15 * FIN + kg * 8;

#pragma unroll 1   // keep rolled: full unroll hoists all B loads -> spill (R1 lesson)
    for (int ks = 0; ks < NK; ++ks) {
        bf16x8 a0, a1;
        const float* p0 = A + (size_t)arow0 * FIN + kg * 8 + ks * 32;
        const float* p1 = A + (size_t)arow1 * FIN + kg * 8 + ks * 32;
        float4 u0 = *(const float4*)p0, u1 = *(const float4*)(p0 + 4);
        float4 w0 = *(const float4*)p1, w1 = *(const float4*)(p1 + 4);
        a0[0] = (short)f2bf(u0.x); a0[1] = (short)f2bf(u0.y);
        a0[2] = (short)f2bf(u0.z); a0[3] = (short)f2bf(u0.w);
        a0[4] = (short)f2bf(u1.x); a0[5] = (short)f2bf(u1.y);
        a0[6] = (short)f2bf(u1.z); a0[7] = (short)f2bf(u1.w);
        a1[0] = (short)f2bf(w0.x); a1[1] = (short)f2bf(w0.y);
        a1[2] = (short)f2bf(w0.z); a1[3] = (short)f2bf(w0.w);
        a1[4] = (short)f2bf(w1.x); a1[5] = (short)f2bf(w1.y);
        a1[6] = (short)f2bf(w1.z); a1[7] = (short)f2bf(w1.w);
#pragma unroll
        for (int c = 0; c < NT; ++c) {
            bf16x8 bfr = *(const bf16x8*)(Bp + (size_t)c * 16 * FIN + ks * 32);
            acc0[c] = __builtin_amdgcn_mfma_f32_16x16x32_bf16(a0, bfr, acc0[c], 0, 0, 0);
            acc1[c] = __builtin_amdgcn_mfma_f32_16x16x32_bf16(a1, bfr, acc1[c], 0, 0, 0);
        }
    }

#pragma unroll
    for (int g = 0; g < 2; ++g) {
        const int rbase = r0 + g * 16 + kg * 4;
#pragma unroll
        for (int j = 0; j < 4; ++j) {
            int row = rbase + j;
            if (row < n) {
                float dscale = dinv[row];
#pragma unroll
                for (int c = 0; c < NT; ++c) {
                    float val = (g == 0) ? acc0[c][j] : acc1[c][j];
                    C[(size_t)row * FOUT + c * 16 + l15] = f2bf(val * dscale);
                }
            }
        }
    }
}

// ---------------- final aggregation (layer 3, f32 out, no relu) ----------------

template <int FIN>
__global__ __launch_bounds__(256) void k_agg_final(const ushort_t* __restrict__ H,
                                                   const float* __restrict__ dinv,
                                                   const int* __restrict__ rowptr,
                                                   const int* __restrict__ csr_src,
                                                   const float* __restrict__ csr_val,
                                                   const float* __restrict__ bias,
                                                   float* __restrict__ out, int n) {
    constexpr int LPN = FIN / 8;       // 4 lanes per node
    constexpr int NPW = 64 / LPN;      // 16 nodes per wave
    const int wave = threadIdx.x >> 6;
    const int lane = threadIdx.x & 63;
    const int sub  = lane / LPN;
    const int f8   = lane % LPN;
    const int node = (blockIdx.x * 4 + wave) * NPW + sub;
    if (node >= n) return;

    const ushort_t* __restrict__ Hf = H + 8 * f8;
    const float sn = dinv[node];
    ushort8_t hv = *(const ushort8_t*)(Hf + (size_t)node * FIN);
    float a[8];
#pragma unroll
    for (int k = 0; k < 8; ++k) a[k] = sn * bf2f(hv[k]);

    agg_body<FIN>(Hf, csr_src, csr_val, rowptr[node], rowptr[node + 1], a);

    float4 bv0 = *(const float4*)(bias + 8 * f8);
    float4 bv1 = *(const float4*)(bias + 8 * f8 + 4);
    a[0] += bv0.x; a[1] += bv0.y; a[2] += bv0.z; a[3] += bv0.w;
    a[4] += bv1.x; a[5] += bv1.y; a[6] += bv1.z; a[7] += bv1.w;
    float* op = out + (size_t)node * FIN + 8 * f8;
    *(float4*)op       = make_float4(a[0], a[1], a[2], a[3]);
    *(float4*)(op + 4) = make_float4(a[4], a[5], a[6], a[7]);
}

// ---------------- launch ----------------

extern "C" void kernel_launch(void* const* d_in, const int* in_sizes, int n_in,
                              void* d_out, int out_size, void* d_ws, size_t ws_size,
                              hipStream_t stream) {
    const float* x    = (const float*)d_in[0];
    const int*   eidx = (const int*)d_in[1];
    const float* ea   = (const float*)d_in[2];
    const float* W1   = (const float*)d_in[3];
    const float* b1   = (const float*)d_in[4];
    const float* W2   = (const float*)d_in[5];
    const float* b2   = (const float*)d_in[6];
    const float* W3   = (const float*)d_in[7];
    const float* b3   = (const float*)d_in[8];

    const int N = in_sizes[0] / 128;
    const int E = in_sizes[2];

    const int nbins = (N + 255) >> BIN_SHIFT;            // 196 for N=50000 (<=256)
    const int epb   = (E + SCAT_NB - 1) / SCAT_NB;       // edges per scatter block
    const int nbc   = nbins * SCAT_NB;                   // bcnt/ebofs length
    const int gBC   = (nbc + BLK - 1) / BLK;

    char*  base = (char*)d_ws;
    size_t off  = 0;
    auto carve = [&](size_t nbytes) -> void* {
        void* p = base + off;
        off = (off + nbytes + 255) & ~(size_t)255;
        return p;
    };
    int*   bcnt      = (int*)  carve((size_t)nbc * 4);
    int*   ebofs     = (int*)  carve((size_t)nbc * 4);
    int*   bsumB     = (int*)  carve((size_t)512 * 4);
    uint2* binned    = (uint2*)carve((size_t)E * 8);
    float* dinv      = (float*)carve((size_t)N * 4);
    int*   rowptr    = (int*)  carve((size_t)(N + 1) * 4);
    int*   csr_src   = (int*)  carve((size_t)E * 4);
    float* csr_val   = (float*)carve((size_t)E * 4);
    ushort_t* bufA   = (ushort_t*)carve((size_t)N * 128 * 2);   // bf16: H'1 / H'3
    ushort_t* bufB   = (ushort_t*)carve((size_t)N * 64 * 2);    // bf16: H'2
    ushort_t* Wt1    = (ushort_t*)carve((size_t)128 * 128 * 2);
    ushort_t* Wt2    = (ushort_t*)carve((size_t)64 * 128 * 2);
    ushort_t* Wt3    = (ushort_t*)carve((size_t)32 * 64 * 2);
    (void)ws_size;

    const int wtot = 128 * 128 + 128 * 64 + 64 * 32;
    const int gPre = SCAT_NB + (wtot + 255) / 256;
    const int gR  = (N + 127) / 128;                     // gemm1 blocks (128 rows/block)
    const int gF  = (N + 31) / 32;                       // fused agg+gemm blocks (32 rows)

    // preprocessing (5 dispatches, scan-based, no global atomics)
    k_pre<<<gPre, BLK, 0, stream>>>(eidx, bcnt, nbins, epb, E, W1, Wt1, W2, Wt2, W3, Wt3);
    k_scan1<<<gBC, BLK, 0, stream>>>(bcnt, ebofs, bsumB, nbc);
    k_scan2x<<<1, BLK, 0, stream>>>(bsumB, gBC);
    k_bin_scatter<<<SCAT_NB, BLK, 0, stream>>>(eidx, ea, ebofs, bsumB, binned, nbins, epb, E);
    k_bin_finish<<<nbins, BLK, 0, stream>>>(binned, ebofs, bsumB, dinv, rowptr,
                                            csr_src, csr_val, nbins, N, E);

    // layer 1 GEMM: H'1 = dinv * (x @ W1)   (reads f32 x directly)
    k_gemm_f32<128, 128><<<gR, BLK, 0, stream>>>(x, Wt1, dinv, bufA, N);

    // fused: G2 = relu(agg(H'1)+b1); H'2 = dinv*(G2 @ W2)
    k_agg_gemm<128, 64><<<gF, BLK, 0, stream>>>(bufA, dinv, rowptr, csr_src, csr_val,
                                                b1, Wt2, bufB, N);

    // fused: G3 = relu(agg(H'2)+b2); H'3 = dinv*(G3 @ W3)
    k_agg_gemm<64, 32><<<gF, BLK, 0, stream>>>(bufB, dinv, rowptr, csr_src, csr_val,
                                               b2, Wt3, bufA, N);

    // final: out = agg(H'3) + b3   (f32, no relu)
    k_agg_final<32><<<(N + 63) / 64, BLK, 0, stream>>>(bufA, dinv, rowptr, csr_src, csr_val,
                                                       b3, (float*)d_out, N);
}